// Round 11
// baseline (499.552 us; speedup 1.0000x reference)
//
#include <hip/hip_runtime.h>
#include <math.h>

// QSAR fused pipeline, one 256-thread block per molecule. B=4096, A=64, D=6, AF=37, BF=6, H=128.
// R11: x2p-row DEDUPLICATION. x2p[a] = max over a's work-member set of x2 rows -> equal
// member-masks give IDENTICAL x2p rows. ~30 nonzero rows collapse to ~7 unique rows.
// P4 builds only unique rows; P5 computes dense logits for unique rows with a k-split
// across the 4 waves (Wo streamed ~once per block) into an LDS D-tile (ds_add_f32),
// then scatters D[urow[a]] + bsum.Wotail + bo to all atoms. Tile loop handles any nu.
// Envelope: (256,4), proven R4 components elsewhere. Spill tripwire: WRITE_SIZE ~128KB.

#define ACC16_FMA(W2V) \
  a0x = fmaf(f0, (W2V).x, a0x); a0y = fmaf(f0, (W2V).y, a0y); \
  a1x = fmaf(f1, (W2V).x, a1x); a1y = fmaf(f1, (W2V).y, a1y); \
  a2x = fmaf(f2, (W2V).x, a2x); a2y = fmaf(f2, (W2V).y, a2y); \
  a3x = fmaf(f3, (W2V).x, a3x); a3y = fmaf(f3, (W2V).y, a3y); \
  a4x = fmaf(f4, (W2V).x, a4x); a4y = fmaf(f4, (W2V).y, a4y); \
  a5x = fmaf(f5, (W2V).x, a5x); a5y = fmaf(f5, (W2V).y, a5y); \
  a6x = fmaf(f6, (W2V).x, a6x); a6y = fmaf(f6, (W2V).y, a6y); \
  a7x = fmaf(f7, (W2V).x, a7x); a7y = fmaf(f7, (W2V).y, a7y);

__device__ __forceinline__ float4 max4(float4 a, float4 b) {
  return make_float4(fmaxf(a.x, b.x), fmaxf(a.y, b.y), fmaxf(a.z, b.z), fmaxf(a.w, b.w));
}

__device__ __forceinline__ float4 nbr_max(const float4* sx4, const int* se, int a, int c4) {
  float4 m = sx4[a * 32 + c4];
#pragma unroll
  for (int d = 0; d < 6; ++d) {
    int e = se[a * 6 + d];
    if (e >= 0) m = max4(m, sx4[e * 32 + c4]);
  }
  return m;
}

__device__ __forceinline__ float4 nbr_sum(const float4* sx4, const int* se, int a, int c4) {
  float4 s = sx4[a * 32 + c4];
#pragma unroll
  for (int d = 0; d < 6; ++d) {
    int e = se[a * 6 + d];
    if (e >= 0) {
      float4 v = sx4[e * 32 + c4];
      s.x += v.x; s.y += v.y; s.z += v.z; s.w += v.w;
    }
  }
  return s;
}

// pool2 over WORK members only; non-work x2 rows are implicitly 0, relu>=0 -> 0-init exact.
__device__ __forceinline__ float4 nbr_wmax(const float4* sx4, const int* se, const int* sdeg,
                                           int a, int c4) {
  float4 m = make_float4(0.f, 0.f, 0.f, 0.f);
  if (sdeg[a] < 6) m = max4(m, sx4[a * 32 + c4]);
#pragma unroll
  for (int d = 0; d < 6; ++d) {
    int e = se[a * 6 + d];
    if (e >= 0 && sdeg[e] < 6) m = max4(m, sx4[e * 32 + c4]);
  }
  return m;
}

__global__ __launch_bounds__(256, 4) void qsar_fused(
    const float* __restrict__ atoms, const float* __restrict__ bonds,
    const int* __restrict__ edges,
    const float* __restrict__ W1, const float* __restrict__ b1,
    const float* __restrict__ W2, const float* __restrict__ b2,
    const float* __restrict__ Wo, const float* __restrict__ bo,
    const float* __restrict__ Wm1, const float* __restrict__ bm1,
    const float* __restrict__ Wm2, const float* __restrict__ bm2,
    const float* __restrict__ Wm3, const float* __restrict__ bm3,
    float* __restrict__ out)
{
  const int b   = blockIdx.x;
  const int tid = threadIdx.x;        // 0..255
  const int wv  = tid >> 6;           // wave 0..3
  const int ln  = tid & 63;           // lane in wave
  const int hid = tid >> 5;           // half-wave unit 0..7
  const int hl  = tid & 31;           // lane in half-wave

  __shared__ float s_x[64 * 128];     // 32768 B
  __shared__ float s_sa[64 * 38];     // conv1 gather; aliased: s_D (P5), s_fp/h1/h2 (P7/8)
  __shared__ float s_wtail[6 * 128];  // Wo rows 128..133 (3 KB)
  __shared__ float s_bsum[64 * 8];
  __shared__ int   s_edges[64 * 6];
  __shared__ unsigned long long s_mask[64];
  __shared__ int   s_deg[64];
  __shared__ int   s_work[64];
  __shared__ int   s_rep[64];
  __shared__ int   s_uidx[64];
  __shared__ int   s_urow[64];        // unique-row index per atom, -1 if zero row
  __shared__ int   s_uniq[64];        // atom id of each unique row
  __shared__ float s_rsum[64];
  __shared__ int   s_nwork, s_nu;

  float4* sx4  = reinterpret_cast<float4*>(s_x);
  float*  s_D  = s_sa;                // 8*128 floats during P5
  float*  s_fp = s_sa;                // 256 floats during P7
  float*  s_h1 = s_sa + 256;
  float*  s_h2 = s_sa + 320;

  // ---------------- P0: stage edges, bsum; zero s_x; init counters --------------------
  {
    const int* ge = edges + (size_t)b * (64 * 6);
    for (int i = tid; i < 64 * 6; i += 256) s_edges[i] = ge[i];
    const float* gb = bonds + (size_t)b * (64 * 36);
    for (int i = tid; i < 64 * 6; i += 256) {
      int a = i / 6, f = i - a * 6;
      float s = 0.f;
#pragma unroll
      for (int d = 0; d < 6; ++d) s += gb[a * 36 + d * 6 + f];
      s_bsum[a * 8 + f] = s;
    }
#pragma unroll
    for (int j = 0; j < 8; ++j) sx4[tid + j * 256] = make_float4(0.f, 0.f, 0.f, 0.f);
    if (tid == 0) { s_nwork = 0; s_nu = 0; }
  }
  __syncthreads();

  // ---------------- P0b: degree + worklist --------------------------------------------
  if (tid < 64) {
    int dcnt = 0;
#pragma unroll
    for (int d = 0; d < 6; ++d) dcnt += (s_edges[tid * 6 + d] >= 0) ? 1 : 0;
    s_deg[tid] = dcnt;
    if (dcnt < 6) { int p = atomicAdd(&s_nwork, 1); s_work[p] = tid; }
  }
  __syncthreads();

  // ---------------- P1a: gather summed feats for all work atoms + P0c: member masks ---
  {
    if (tid < 64) {
      unsigned long long m = 0ull;
      if (s_deg[tid] < 6) m |= 1ull << tid;
#pragma unroll
      for (int d = 0; d < 6; ++d) {
        int e = s_edges[tid * 6 + d];
        if (e >= 0 && s_deg[e] < 6) m |= 1ull << e;
      }
      s_mask[tid] = m;
    }
    const int nw = s_nwork;
    const float* ga = atoms + (size_t)b * (64 * 37);
    for (int i = tid; i < nw * 37; i += 256) {
      int wi = i / 37, k = i - wi * 37;
      int a = s_work[wi];
      float f = ga[a * 37 + k];
#pragma unroll
      for (int d = 0; d < 6; ++d) {
        int e = s_edges[a * 6 + d];
        if (e >= 0) f += ga[e * 37 + k];
      }
      s_sa[wi * 38 + k] = f;
    }
  }
  __syncthreads();

  // ---------------- P1b: conv1 GEMV (half-wave per atom, R4-proven) + P0d: rep scan ---
  {
    if (tid < 64) {
      const unsigned long long m = s_mask[tid];
      int rep = tid;
      for (int bb = 0; bb < tid; ++bb)
        if (s_mask[bb] == m) { rep = bb; break; }
      s_rep[tid] = rep;
      if (m != 0ull && rep == tid) {
        int u = atomicAdd(&s_nu, 1);
        s_uniq[u] = tid;
        s_uidx[tid] = u;
      }
    }
    const int nw = s_nwork;
    const int c0 = hl * 4;
    for (int w = hid; w < nw; w += 8) {
      const int a = s_work[w];
      const int d = s_deg[a];
      const float4* wdf4 = reinterpret_cast<const float4*>(W1 + d * (43 * 128));
      float4 acc = *reinterpret_cast<const float4*>(&b1[d * 128 + c0]);
#pragma unroll 4
      for (int k = 0; k < 37; ++k) {
        const float ff = s_sa[w * 38 + k];
        const float4 w4 = wdf4[k * 32 + hl];
        acc.x = fmaf(ff, w4.x, acc.x); acc.y = fmaf(ff, w4.y, acc.y);
        acc.z = fmaf(ff, w4.z, acc.z); acc.w = fmaf(ff, w4.w, acc.w);
      }
#pragma unroll
      for (int kk = 0; kk < 6; ++kk) {
        const float ff = s_bsum[a * 8 + kk];
        const float4 w4 = wdf4[(37 + kk) * 32 + hl];
        acc.x = fmaf(ff, w4.x, acc.x); acc.y = fmaf(ff, w4.y, acc.y);
        acc.z = fmaf(ff, w4.z, acc.z); acc.w = fmaf(ff, w4.w, acc.w);
      }
      *reinterpret_cast<float4*>(&s_x[a * 128 + c0]) =
          make_float4(fmaxf(acc.x, 0.f), fmaxf(acc.y, 0.f),
                      fmaxf(acc.z, 0.f), fmaxf(acc.w, 0.f));
    }
  }
  __syncthreads();

  // ---------------- P2: pool1 in place (all rows) + P0e: urow --------------------------
  {
    if (tid < 64)
      s_urow[tid] = (s_mask[tid] != 0ull) ? s_uidx[s_rep[tid]] : -1;
    float4 v0 = nbr_max(sx4, s_edges, (tid + 0 * 256) >> 5, tid & 31);
    float4 v1 = nbr_max(sx4, s_edges, (tid + 1 * 256) >> 5, tid & 31);
    float4 v2 = nbr_max(sx4, s_edges, (tid + 2 * 256) >> 5, tid & 31);
    float4 v3 = nbr_max(sx4, s_edges, (tid + 3 * 256) >> 5, tid & 31);
    float4 v4 = nbr_max(sx4, s_edges, (tid + 4 * 256) >> 5, tid & 31);
    float4 v5 = nbr_max(sx4, s_edges, (tid + 5 * 256) >> 5, tid & 31);
    float4 v6 = nbr_max(sx4, s_edges, (tid + 6 * 256) >> 5, tid & 31);
    float4 v7 = nbr_max(sx4, s_edges, (tid + 7 * 256) >> 5, tid & 31);
    __syncthreads();
    sx4[tid + 0 * 256] = v0; sx4[tid + 1 * 256] = v1;
    sx4[tid + 2 * 256] = v2; sx4[tid + 3 * 256] = v3;
    sx4[tid + 4 * 256] = v4; sx4[tid + 5 * 256] = v5;
    sx4[tid + 6 * 256] = v6; sx4[tid + 7 * 256] = v7;
  }
  __syncthreads();

  // ---------------- P2b: ysum for work rows in place -----------------------------------
  {
    const float4 z = make_float4(0.f, 0.f, 0.f, 0.f);
    float4 v0 = z, v1 = z, v2 = z, v3 = z, v4 = z, v5 = z, v6 = z, v7 = z;
    if (s_deg[(tid + 0 * 256) >> 5] < 6) v0 = nbr_sum(sx4, s_edges, (tid + 0 * 256) >> 5, tid & 31);
    if (s_deg[(tid + 1 * 256) >> 5] < 6) v1 = nbr_sum(sx4, s_edges, (tid + 1 * 256) >> 5, tid & 31);
    if (s_deg[(tid + 2 * 256) >> 5] < 6) v2 = nbr_sum(sx4, s_edges, (tid + 2 * 256) >> 5, tid & 31);
    if (s_deg[(tid + 3 * 256) >> 5] < 6) v3 = nbr_sum(sx4, s_edges, (tid + 3 * 256) >> 5, tid & 31);
    if (s_deg[(tid + 4 * 256) >> 5] < 6) v4 = nbr_sum(sx4, s_edges, (tid + 4 * 256) >> 5, tid & 31);
    if (s_deg[(tid + 5 * 256) >> 5] < 6) v5 = nbr_sum(sx4, s_edges, (tid + 5 * 256) >> 5, tid & 31);
    if (s_deg[(tid + 6 * 256) >> 5] < 6) v6 = nbr_sum(sx4, s_edges, (tid + 6 * 256) >> 5, tid & 31);
    if (s_deg[(tid + 7 * 256) >> 5] < 6) v7 = nbr_sum(sx4, s_edges, (tid + 7 * 256) >> 5, tid & 31);
    __syncthreads();
    if (s_deg[(tid + 0 * 256) >> 5] < 6) sx4[tid + 0 * 256] = v0;
    if (s_deg[(tid + 1 * 256) >> 5] < 6) sx4[tid + 1 * 256] = v1;
    if (s_deg[(tid + 2 * 256) >> 5] < 6) sx4[tid + 2 * 256] = v2;
    if (s_deg[(tid + 3 * 256) >> 5] < 6) sx4[tid + 3 * 256] = v3;
    if (s_deg[(tid + 4 * 256) >> 5] < 6) sx4[tid + 4 * 256] = v4;
    if (s_deg[(tid + 5 * 256) >> 5] < 6) sx4[tid + 5 * 256] = v5;
    if (s_deg[(tid + 6 * 256) >> 5] < 6) sx4[tid + 6 * 256] = v6;
    if (s_deg[(tid + 7 * 256) >> 5] < 6) sx4[tid + 7 * 256] = v7;
  }
  __syncthreads();

  // ---------------- P3: conv2 (half-wave per atom, own-row read/write, R4-proven) ------
  {
    const int nw = s_nwork;
    const int c0 = hl * 4;
    for (int w = hid; w < nw; w += 8) {
      const int a = s_work[w];
      const int d = s_deg[a];
      const float4* wdf4 = reinterpret_cast<const float4*>(W2 + d * (134 * 128));
      float4 acc = *reinterpret_cast<const float4*>(&b2[d * 128 + c0]);
#pragma unroll 4
      for (int k = 0; k < 128; ++k) {
        const float ff = s_x[a * 128 + k];
        const float4 w4 = wdf4[k * 32 + hl];
        acc.x = fmaf(ff, w4.x, acc.x); acc.y = fmaf(ff, w4.y, acc.y);
        acc.z = fmaf(ff, w4.z, acc.z); acc.w = fmaf(ff, w4.w, acc.w);
      }
#pragma unroll
      for (int kk = 0; kk < 6; ++kk) {
        const float ff = s_bsum[a * 8 + kk];
        const float4 w4 = wdf4[(128 + kk) * 32 + hl];
        acc.x = fmaf(ff, w4.x, acc.x); acc.y = fmaf(ff, w4.y, acc.y);
        acc.z = fmaf(ff, w4.z, acc.z); acc.w = fmaf(ff, w4.w, acc.w);
      }
      *reinterpret_cast<float4*>(&s_x[a * 128 + c0]) =
          make_float4(fmaxf(acc.x, 0.f), fmaxf(acc.y, 0.f),
                      fmaxf(acc.z, 0.f), fmaxf(acc.w, 0.f));
    }
  }
  __syncthreads();

  // ---------------- P4: pool2 for UNIQUE rows only (register-stage + scatter) ----------
  // Reads x2 from work rows; writes x2p ONLY at unique-rep rows (after all reads).
  {
    const int lim = s_nu * 32;          // float4 elements
    const float4 z = make_float4(0.f, 0.f, 0.f, 0.f);
    float4 v0 = z, v1 = z, v2 = z, v3 = z, v4 = z, v5 = z, v6 = z, v7 = z;
    const int i0 = tid, i1 = tid + 256, i2 = tid + 512, i3 = tid + 768;
    const int i4 = tid + 1024, i5 = tid + 1280, i6 = tid + 1536, i7 = tid + 1792;
    if (i0 < lim) v0 = nbr_wmax(sx4, s_edges, s_deg, s_uniq[i0 >> 5], i0 & 31);
    if (i1 < lim) v1 = nbr_wmax(sx4, s_edges, s_deg, s_uniq[i1 >> 5], i1 & 31);
    if (i2 < lim) v2 = nbr_wmax(sx4, s_edges, s_deg, s_uniq[i2 >> 5], i2 & 31);
    if (i3 < lim) v3 = nbr_wmax(sx4, s_edges, s_deg, s_uniq[i3 >> 5], i3 & 31);
    if (i4 < lim) v4 = nbr_wmax(sx4, s_edges, s_deg, s_uniq[i4 >> 5], i4 & 31);
    if (i5 < lim) v5 = nbr_wmax(sx4, s_edges, s_deg, s_uniq[i5 >> 5], i5 & 31);
    if (i6 < lim) v6 = nbr_wmax(sx4, s_edges, s_deg, s_uniq[i6 >> 5], i6 & 31);
    if (i7 < lim) v7 = nbr_wmax(sx4, s_edges, s_deg, s_uniq[i7 >> 5], i7 & 31);
    __syncthreads();
    if (i0 < lim) sx4[s_uniq[i0 >> 5] * 32 + (i0 & 31)] = v0;
    if (i1 < lim) sx4[s_uniq[i1 >> 5] * 32 + (i1 & 31)] = v1;
    if (i2 < lim) sx4[s_uniq[i2 >> 5] * 32 + (i2 & 31)] = v2;
    if (i3 < lim) sx4[s_uniq[i3 >> 5] * 32 + (i3 & 31)] = v3;
    if (i4 < lim) sx4[s_uniq[i4 >> 5] * 32 + (i4 & 31)] = v4;
    if (i5 < lim) sx4[s_uniq[i5 >> 5] * 32 + (i5 & 31)] = v5;
    if (i6 < lim) sx4[s_uniq[i6 >> 5] * 32 + (i6 & 31)] = v6;
    if (i7 < lim) sx4[s_uniq[i7 >> 5] * 32 + (i7 & 31)] = v7;
  }
  __syncthreads();

  // ---------------- P5: dense logits for unique rows, k-split + LDS atomics ------------
  // Tiles of 8 unique rows. Per tile: zero D; wave wv accumulates k in [32wv,32wv+32)
  // (1 float2 Wo load + 8 broadcasts + 16 FMA per k) -> ds_add into s_D[8][128];
  // barrier; scatter logits[a] = D[urow[a]] + bsum[a].Wotail + bo for atoms of this tile
  // (zero-mask atoms handled in tile 0 with no D term). Tile t writes only rows whose
  // urow is in tile t; later tiles' dense reads touch only THEIR unique rows -> safe.
  {
    for (int i = tid; i < 768; i += 256) s_wtail[i] = Wo[128 * 128 + i];
    const int nu = s_nu;
    const int ntile = (nu == 0) ? 1 : ((nu + 7) >> 3);
    const float2* Wof2 = reinterpret_cast<const float2*>(Wo);
    for (int t = 0; t < ntile; ++t) {
      for (int i = tid; i < 1024; i += 256) s_D[i] = 0.f;
      __syncthreads();
      {
        const int u0 = t * 8;
        const int b0 = ((u0 + 0 < nu) ? s_uniq[u0 + 0] : 0) * 128;
        const int b1r = ((u0 + 1 < nu) ? s_uniq[u0 + 1] : 0) * 128;
        const int b2r = ((u0 + 2 < nu) ? s_uniq[u0 + 2] : 0) * 128;
        const int b3 = ((u0 + 3 < nu) ? s_uniq[u0 + 3] : 0) * 128;
        const int b4 = ((u0 + 4 < nu) ? s_uniq[u0 + 4] : 0) * 128;
        const int b5 = ((u0 + 5 < nu) ? s_uniq[u0 + 5] : 0) * 128;
        const int b6 = ((u0 + 6 < nu) ? s_uniq[u0 + 6] : 0) * 128;
        const int b7 = ((u0 + 7 < nu) ? s_uniq[u0 + 7] : 0) * 128;
        const float g0 = (u0 + 0 < nu) ? 1.f : 0.f, g1 = (u0 + 1 < nu) ? 1.f : 0.f;
        const float g2 = (u0 + 2 < nu) ? 1.f : 0.f, g3 = (u0 + 3 < nu) ? 1.f : 0.f;
        const float g4 = (u0 + 4 < nu) ? 1.f : 0.f, g5 = (u0 + 5 < nu) ? 1.f : 0.f;
        const float g6 = (u0 + 6 < nu) ? 1.f : 0.f, g7 = (u0 + 7 < nu) ? 1.f : 0.f;
        const int k0 = wv * 32;
        float a0x = 0.f, a0y = 0.f, a1x = 0.f, a1y = 0.f;
        float a2x = 0.f, a2y = 0.f, a3x = 0.f, a3y = 0.f;
        float a4x = 0.f, a4y = 0.f, a5x = 0.f, a5y = 0.f;
        float a6x = 0.f, a6y = 0.f, a7x = 0.f, a7y = 0.f;
#pragma unroll 4
        for (int j = 0; j < 32; ++j) {
          const int k = k0 + j;
          const float2 w = Wof2[k * 64 + ln];
          const float f0 = g0 * s_x[b0 + k],  f1 = g1 * s_x[b1r + k];
          const float f2 = g2 * s_x[b2r + k], f3 = g3 * s_x[b3 + k];
          const float f4 = g4 * s_x[b4 + k],  f5 = g5 * s_x[b5 + k];
          const float f6 = g6 * s_x[b6 + k],  f7 = g7 * s_x[b7 + k];
          ACC16_FMA(w)
        }
        const int cc = 2 * ln;
        atomicAdd(&s_D[0 * 128 + cc], a0x); atomicAdd(&s_D[0 * 128 + cc + 1], a0y);
        atomicAdd(&s_D[1 * 128 + cc], a1x); atomicAdd(&s_D[1 * 128 + cc + 1], a1y);
        atomicAdd(&s_D[2 * 128 + cc], a2x); atomicAdd(&s_D[2 * 128 + cc + 1], a2y);
        atomicAdd(&s_D[3 * 128 + cc], a3x); atomicAdd(&s_D[3 * 128 + cc + 1], a3y);
        atomicAdd(&s_D[4 * 128 + cc], a4x); atomicAdd(&s_D[4 * 128 + cc + 1], a4y);
        atomicAdd(&s_D[5 * 128 + cc], a5x); atomicAdd(&s_D[5 * 128 + cc + 1], a5y);
        atomicAdd(&s_D[6 * 128 + cc], a6x); atomicAdd(&s_D[6 * 128 + cc + 1], a6y);
        atomicAdd(&s_D[7 * 128 + cc], a7x); atomicAdd(&s_D[7 * 128 + cc + 1], a7y);
      }
      __syncthreads();
      for (int e = tid; e < 64 * 128; e += 256) {
        const int a = e >> 7, c = e & 127;
        const int ur = s_urow[a];
        const int ta = (ur < 0) ? 0 : (ur >> 3);
        if (ta == t) {
          float acc = bo[c];
#pragma unroll
          for (int kk = 0; kk < 6; ++kk)
            acc = fmaf(s_bsum[a * 8 + kk], s_wtail[kk * 128 + c], acc);
          if (ur >= 0) acc += s_D[(ur & 7) * 128 + c];
          s_x[a * 128 + c] = acc;
        }
      }
      __syncthreads();
    }
  }

  // ---------------- P6: per-atom softmax over 128, 4 lanes/atom, in registers ----------
  {
    const int a = tid >> 2, q = tid & 3;
    float* base = &s_x[a * 128 + q * 32];
    const float4 v0 = *reinterpret_cast<const float4*>(base + ((0 + tid) & 7) * 4);
    const float4 v1 = *reinterpret_cast<const float4*>(base + ((1 + tid) & 7) * 4);
    const float4 v2 = *reinterpret_cast<const float4*>(base + ((2 + tid) & 7) * 4);
    const float4 v3 = *reinterpret_cast<const float4*>(base + ((3 + tid) & 7) * 4);
    const float4 v4 = *reinterpret_cast<const float4*>(base + ((4 + tid) & 7) * 4);
    const float4 v5 = *reinterpret_cast<const float4*>(base + ((5 + tid) & 7) * 4);
    const float4 v6 = *reinterpret_cast<const float4*>(base + ((6 + tid) & 7) * 4);
    const float4 v7 = *reinterpret_cast<const float4*>(base + ((7 + tid) & 7) * 4);
    float mx = fmaxf(fmaxf(fmaxf(v0.x, v0.y), fmaxf(v0.z, v0.w)),
                     fmaxf(fmaxf(v1.x, v1.y), fmaxf(v1.z, v1.w)));
    mx = fmaxf(mx, fmaxf(fmaxf(fmaxf(v2.x, v2.y), fmaxf(v2.z, v2.w)),
                         fmaxf(fmaxf(v3.x, v3.y), fmaxf(v3.z, v3.w))));
    mx = fmaxf(mx, fmaxf(fmaxf(fmaxf(v4.x, v4.y), fmaxf(v4.z, v4.w)),
                         fmaxf(fmaxf(v5.x, v5.y), fmaxf(v5.z, v5.w))));
    mx = fmaxf(mx, fmaxf(fmaxf(fmaxf(v6.x, v6.y), fmaxf(v6.z, v6.w)),
                         fmaxf(fmaxf(v7.x, v7.y), fmaxf(v7.z, v7.w))));
    mx = fmaxf(mx, __shfl_xor(mx, 1));
    mx = fmaxf(mx, __shfl_xor(mx, 2));
    float sm = 0.f;
    float4 e0, e1, e2, e3, e4, e5, e6, e7;
    e0.x = __expf(v0.x - mx); e0.y = __expf(v0.y - mx); e0.z = __expf(v0.z - mx); e0.w = __expf(v0.w - mx);
    e1.x = __expf(v1.x - mx); e1.y = __expf(v1.y - mx); e1.z = __expf(v1.z - mx); e1.w = __expf(v1.w - mx);
    e2.x = __expf(v2.x - mx); e2.y = __expf(v2.y - mx); e2.z = __expf(v2.z - mx); e2.w = __expf(v2.w - mx);
    e3.x = __expf(v3.x - mx); e3.y = __expf(v3.y - mx); e3.z = __expf(v3.z - mx); e3.w = __expf(v3.w - mx);
    e4.x = __expf(v4.x - mx); e4.y = __expf(v4.y - mx); e4.z = __expf(v4.z - mx); e4.w = __expf(v4.w - mx);
    e5.x = __expf(v5.x - mx); e5.y = __expf(v5.y - mx); e5.z = __expf(v5.z - mx); e5.w = __expf(v5.w - mx);
    e6.x = __expf(v6.x - mx); e6.y = __expf(v6.y - mx); e6.z = __expf(v6.z - mx); e6.w = __expf(v6.w - mx);
    e7.x = __expf(v7.x - mx); e7.y = __expf(v7.y - mx); e7.z = __expf(v7.z - mx); e7.w = __expf(v7.w - mx);
    sm += e0.x + e0.y + e0.z + e0.w; sm += e1.x + e1.y + e1.z + e1.w;
    sm += e2.x + e2.y + e2.z + e2.w; sm += e3.x + e3.y + e3.z + e3.w;
    sm += e4.x + e4.y + e4.z + e4.w; sm += e5.x + e5.y + e5.z + e5.w;
    sm += e6.x + e6.y + e6.z + e6.w; sm += e7.x + e7.y + e7.z + e7.w;
    *reinterpret_cast<float4*>(base + ((0 + tid) & 7) * 4) = e0;
    *reinterpret_cast<float4*>(base + ((1 + tid) & 7) * 4) = e1;
    *reinterpret_cast<float4*>(base + ((2 + tid) & 7) * 4) = e2;
    *reinterpret_cast<float4*>(base + ((3 + tid) & 7) * 4) = e3;
    *reinterpret_cast<float4*>(base + ((4 + tid) & 7) * 4) = e4;
    *reinterpret_cast<float4*>(base + ((5 + tid) & 7) * 4) = e5;
    *reinterpret_cast<float4*>(base + ((6 + tid) & 7) * 4) = e6;
    *reinterpret_cast<float4*>(base + ((7 + tid) & 7) * 4) = e7;
    sm += __shfl_xor(sm, 1);
    sm += __shfl_xor(sm, 2);
    if (q == 0) s_rsum[a] = (s_deg[a] != 0) ? (1.f / sm) : 0.f;
  }
  __syncthreads();

  // ---------------- P7: fingerprint (s_fp aliases dead s_D/s_sa) -----------------------
  {
    const int c = tid & 127, half = tid >> 7;
    float s = 0.f;
    for (int a2 = half * 32; a2 < half * 32 + 32; ++a2)
      s = fmaf(s_x[a2 * 128 + c], s_rsum[a2], s);
    s_fp[half * 128 + c] = s;
  }
  __syncthreads();
  if (tid < 128) s_fp[tid] += s_fp[128 + tid];
  __syncthreads();

  // ---------------- P8: MLP head, 4 lanes/output + shfl reduce -------------------------
  {
    const int o = tid >> 2, ks = tid & 3;
    float acc = 0.f;
#pragma unroll 8
    for (int tt = 0; tt < 32; ++tt) {
      const int k = ks * 32 + tt;
      acc = fmaf(s_fp[k], Wm1[k * 64 + o], acc);
    }
    acc += __shfl_xor(acc, 1);
    acc += __shfl_xor(acc, 2);
    if (ks == 0) s_h1[o] = fmaxf(acc + bm1[o], 0.f);
  }
  __syncthreads();
  if (tid < 128) {
    const int o = tid >> 2, ks = tid & 3;
    float acc = 0.f;
#pragma unroll
    for (int tt = 0; tt < 16; ++tt) {
      const int k = ks * 16 + tt;
      acc = fmaf(s_h1[k], Wm2[k * 32 + o], acc);
    }
    acc += __shfl_xor(acc, 1);
    acc += __shfl_xor(acc, 2);
    if (ks == 0) s_h2[o] = fmaxf(acc + bm2[o], 0.f);
  }
  __syncthreads();
  if (tid < 64) {
    float p = (tid < 32) ? s_h2[tid] * Wm3[tid] : 0.f;
#pragma unroll
    for (int off = 32; off > 0; off >>= 1) p += __shfl_xor(p, off);
    if (tid == 0) out[b] = p + bm3[0];
  }
}

extern "C" void kernel_launch(void* const* d_in, const int* in_sizes, int n_in,
                              void* d_out, int out_size, void* d_ws, size_t ws_size,
                              hipStream_t stream) {
  const float* atoms = (const float*)d_in[0];
  const float* bonds = (const float*)d_in[1];
  const int*   edges = (const int*)d_in[2];
  const float* W1  = (const float*)d_in[3];
  const float* b1  = (const float*)d_in[4];
  const float* W2  = (const float*)d_in[5];
  const float* b2  = (const float*)d_in[6];
  const float* Wo  = (const float*)d_in[7];
  const float* bo  = (const float*)d_in[8];
  const float* Wm1 = (const float*)d_in[9];
  const float* bm1 = (const float*)d_in[10];
  const float* Wm2 = (const float*)d_in[11];
  const float* bm2 = (const float*)d_in[12];
  const float* Wm3 = (const float*)d_in[13];
  const float* bm3 = (const float*)d_in[14];
  float* out = (float*)d_out;

  const int B = out_size;  // 4096 molecules
  qsar_fused<<<dim3(B), dim3(256), 0, stream>>>(
      atoms, bonds, edges, W1, b1, W2, b2, Wo, bo,
      Wm1, bm1, Wm2, bm2, Wm3, bm3, out);
}

// Round 12
// 372.480 us; speedup vs baseline: 1.3411x; 1.3411x over previous
//
#include <hip/hip_runtime.h>
#include <math.h>

// QSAR fused pipeline, ONE BLOCK OF 512 THREADS PER MOLECULE (R7 base, 239us proven).
// B=4096, A=64, D=6, AF=37, BF=6, H=128.
// R12 changes vs R7 (only two, both critical-path cuts):
//  1) P5 dedup: x2p rows with equal work-member masks are IDENTICAL (~7 unique rows).
//     Dense: 16 half-wave units = 8 row-slots x 2 k-chunks(64) -> disjoint D0/D1 LDS
//     writes (no atomics, no zeroing). Scatter: logits[a]=D0+D1[urow]+bo+bsum.Wotail.
//  2) conv2 quarter-wave k-split: lanes 0-15 k<64, lanes 16-31 k>=64, 8 cols/lane,
//     shfl_xor(16) reduce -> 134-iter path becomes 67.
// Envelope: (512,8) (R7: VGPR 32, no spill). Spill tripwire: WRITE_SIZE ~128 KB.

__device__ __forceinline__ float4 max4(float4 a, float4 b) {
  return make_float4(fmaxf(a.x, b.x), fmaxf(a.y, b.y), fmaxf(a.z, b.z), fmaxf(a.w, b.w));
}

__device__ __forceinline__ float4 nbr_max(const float4* sx4, const int* se, int a, int c4) {
  float4 m = sx4[a * 32 + c4];
#pragma unroll
  for (int d = 0; d < 6; ++d) {
    int e = se[a * 6 + d];
    if (e >= 0) m = max4(m, sx4[e * 32 + c4]);
  }
  return m;
}

__device__ __forceinline__ float4 nbr_sum(const float4* sx4, const int* se, int a, int c4) {
  float4 s = sx4[a * 32 + c4];
#pragma unroll
  for (int d = 0; d < 6; ++d) {
    int e = se[a * 6 + d];
    if (e >= 0) {
      float4 v = sx4[e * 32 + c4];
      s.x += v.x; s.y += v.y; s.z += v.z; s.w += v.w;
    }
  }
  return s;
}

// pool2: max over WORK members only; non-work x2 rows implicitly 0, relu>=0 -> 0-init exact.
__device__ __forceinline__ float4 nbr_wmax(const float4* sx4, const int* se, const int* sdeg,
                                           int a, int c4) {
  float4 m = make_float4(0.f, 0.f, 0.f, 0.f);
  if (sdeg[a] < 6) m = max4(m, sx4[a * 32 + c4]);
#pragma unroll
  for (int d = 0; d < 6; ++d) {
    int e = se[a * 6 + d];
    if (e >= 0 && sdeg[e] < 6) m = max4(m, sx4[e * 32 + c4]);
  }
  return m;
}

__global__ __launch_bounds__(512, 8) void qsar_fused(
    const float* __restrict__ atoms, const float* __restrict__ bonds,
    const int* __restrict__ edges,
    const float* __restrict__ W1, const float* __restrict__ b1,
    const float* __restrict__ W2, const float* __restrict__ b2,
    const float* __restrict__ Wo, const float* __restrict__ bo,
    const float* __restrict__ Wm1, const float* __restrict__ bm1,
    const float* __restrict__ Wm2, const float* __restrict__ bm2,
    const float* __restrict__ Wm3, const float* __restrict__ bm3,
    float* __restrict__ out)
{
  const int b    = blockIdx.x;
  const int tid  = threadIdx.x;        // 0..511
  const int hid  = tid >> 5;           // half-wave unit id 0..15
  const int hl   = tid & 31;           // lane in half-wave

  __shared__ float s_x[64 * 128];      // 32768 B
  __shared__ float s_u[2944];          // union: conv1 gather(608) | D0D1(2048) | fp/h1/h2
                                       //        + wtail(768)@2048 + bo(128)@2816
  __shared__ float s_bsum[64 * 8];     // 2048 B
  __shared__ int   s_edges[64 * 6];    // 1536 B
  __shared__ unsigned long long s_mask[64];
  __shared__ int   s_deg[64];
  __shared__ int   s_work[64];         // deg<6 atoms
  __shared__ int   s_rep[64];
  __shared__ int   s_uidx[64];
  __shared__ int   s_urow[64];         // unique-row index per atom, -1 if zero x2p row
  __shared__ int   s_uniq[64];         // atom id of each unique row
  __shared__ float s_rsum[64];
  __shared__ int   s_nwork, s_nu;

  float4* sx4     = reinterpret_cast<float4*>(s_x);
  float*  s_sa    = s_u;               // conv1 gather (16*38=608)
  float*  s_D     = s_u;               // D0=[0..1023], D1=[1024..2047] during P5
  float*  s_wtail = s_u + 2048;        // 768
  float*  s_bo    = s_u + 2816;        // 128
  float*  s_fp    = s_u;               // 512 (P7)
  float*  s_h1    = s_u + 512;         // 64
  float*  s_h2    = s_u + 576;         // 32

  // ---------------- P0: stage edges, bsum; zero s_x; reset counters -------------------
  {
    const int* ge = edges + (size_t)b * (64 * 6);
    for (int i = tid; i < 64 * 6; i += 512) s_edges[i] = ge[i];
    const float* gb = bonds + (size_t)b * (64 * 36);
    for (int i = tid; i < 64 * 6; i += 512) {
      int a = i / 6, f = i - a * 6;
      float s = 0.f;
#pragma unroll
      for (int d = 0; d < 6; ++d) s += gb[a * 36 + d * 6 + f];
      s_bsum[a * 8 + f] = s;
    }
#pragma unroll
    for (int j = 0; j < 4; ++j) sx4[tid + j * 512] = make_float4(0.f, 0.f, 0.f, 0.f);
    if (tid == 0) { s_nwork = 0; s_nu = 0; }
  }
  __syncthreads();

  // ---------------- P0b: degree + worklist --------------------------------------------
  if (tid < 64) {
    int dcnt = 0;
#pragma unroll
    for (int d = 0; d < 6; ++d) dcnt += (s_edges[tid * 6 + d] >= 0) ? 1 : 0;
    s_deg[tid] = dcnt;
    if (dcnt < 6) { int p = atomicAdd(&s_nwork, 1); s_work[p] = tid; }
  }
  __syncthreads();

  // ---------------- P0c: work-member masks (x2p identity) ------------------------------
  if (tid < 64) {
    unsigned long long m = 0ull;
    if (s_deg[tid] < 6) m |= 1ull << tid;
#pragma unroll
    for (int d = 0; d < 6; ++d) {
      int e = s_edges[tid * 6 + d];
      if (e >= 0 && s_deg[e] < 6) m |= 1ull << e;
    }
    s_mask[tid] = m;
  }
  __syncthreads();

  // ---------------- P1: rep scan (tid<64) + conv1 (16 half-wave units, R7-proven) -----
  {
    if (tid < 64) {
      const unsigned long long m = s_mask[tid];
      int rep = tid;
      for (int bb = 0; bb < tid; ++bb)
        if (s_mask[bb] == m) { rep = bb; break; }
      s_rep[tid] = rep;
      if (m != 0ull && rep == tid) {
        int u = atomicAdd(&s_nu, 1);
        s_uniq[u] = tid;
        s_uidx[tid] = u;
      }
    }
    const int nw = s_nwork;
    const float* ga = atoms + (size_t)b * (64 * 37);
    const int c0 = hl * 4;
    for (int cb = 0; cb < nw; cb += 16) {
      const int cnt = (nw - cb < 16) ? (nw - cb) : 16;
      for (int i = tid; i < cnt * 37; i += 512) {
        int wi = i / 37, k = i - wi * 37;
        int a = s_work[cb + wi];
        float f = ga[a * 37 + k];
#pragma unroll
        for (int d = 0; d < 6; ++d) {
          int e = s_edges[a * 6 + d];
          if (e >= 0) f += ga[e * 37 + k];
        }
        s_sa[wi * 38 + k] = f;
      }
      __syncthreads();
      for (int w = hid; w < cnt; w += 16) {
        const int a = s_work[cb + w];
        const int d = s_deg[a];
        const float4* wdf4 = reinterpret_cast<const float4*>(W1 + d * (43 * 128));
        float4 acc = *reinterpret_cast<const float4*>(&b1[d * 128 + c0]);
#pragma unroll 4
        for (int k = 0; k < 37; ++k) {
          const float ff = s_sa[w * 38 + k];
          const float4 w4 = wdf4[k * 32 + hl];
          acc.x = fmaf(ff, w4.x, acc.x); acc.y = fmaf(ff, w4.y, acc.y);
          acc.z = fmaf(ff, w4.z, acc.z); acc.w = fmaf(ff, w4.w, acc.w);
        }
#pragma unroll
        for (int kk = 0; kk < 6; ++kk) {
          const float ff = s_bsum[a * 8 + kk];
          const float4 w4 = wdf4[(37 + kk) * 32 + hl];
          acc.x = fmaf(ff, w4.x, acc.x); acc.y = fmaf(ff, w4.y, acc.y);
          acc.z = fmaf(ff, w4.z, acc.z); acc.w = fmaf(ff, w4.w, acc.w);
        }
        *reinterpret_cast<float4*>(&s_x[a * 128 + c0]) =
            make_float4(fmaxf(acc.x, 0.f), fmaxf(acc.y, 0.f),
                        fmaxf(acc.z, 0.f), fmaxf(acc.w, 0.f));
      }
      __syncthreads();
    }
  }
  __syncthreads();

  // ---------------- P2: pool1 in place (all rows) + urow finalize ----------------------
  {
    if (tid < 64)
      s_urow[tid] = (s_mask[tid] != 0ull) ? s_uidx[s_rep[tid]] : -1;
    float4 v0 = nbr_max(sx4, s_edges, (tid + 0 * 512) >> 5, tid & 31);
    float4 v1 = nbr_max(sx4, s_edges, (tid + 1 * 512) >> 5, tid & 31);
    float4 v2 = nbr_max(sx4, s_edges, (tid + 2 * 512) >> 5, tid & 31);
    float4 v3 = nbr_max(sx4, s_edges, (tid + 3 * 512) >> 5, tid & 31);
    __syncthreads();
    sx4[tid + 0 * 512] = v0; sx4[tid + 1 * 512] = v1;
    sx4[tid + 2 * 512] = v2; sx4[tid + 3 * 512] = v3;
  }
  __syncthreads();

  // ---------------- P2b: ysum for work rows in place ----------------------------------
  {
    const float4 z = make_float4(0.f, 0.f, 0.f, 0.f);
    float4 v0 = z, v1 = z, v2 = z, v3 = z;
    if (s_deg[(tid + 0 * 512) >> 5] < 6) v0 = nbr_sum(sx4, s_edges, (tid + 0 * 512) >> 5, tid & 31);
    if (s_deg[(tid + 1 * 512) >> 5] < 6) v1 = nbr_sum(sx4, s_edges, (tid + 1 * 512) >> 5, tid & 31);
    if (s_deg[(tid + 2 * 512) >> 5] < 6) v2 = nbr_sum(sx4, s_edges, (tid + 2 * 512) >> 5, tid & 31);
    if (s_deg[(tid + 3 * 512) >> 5] < 6) v3 = nbr_sum(sx4, s_edges, (tid + 3 * 512) >> 5, tid & 31);
    __syncthreads();
    if (s_deg[(tid + 0 * 512) >> 5] < 6) sx4[tid + 0 * 512] = v0;
    if (s_deg[(tid + 1 * 512) >> 5] < 6) sx4[tid + 1 * 512] = v1;
    if (s_deg[(tid + 2 * 512) >> 5] < 6) sx4[tid + 2 * 512] = v2;
    if (s_deg[(tid + 3 * 512) >> 5] < 6) sx4[tid + 3 * 512] = v3;
  }
  __syncthreads();

  // ---------------- P3: conv2, half-wave unit/atom, quarter-wave k-split --------------
  // qh=hl>>4 selects k-chunk (0: k<64 + bsum 0..2, 1: k>=64 + bsum 3..5). 8 cols/lane.
  // Reduce across qh via shfl_xor(16); qh==0 lanes write. All reads of row a precede
  // the shfl (data dep) which precedes the write (program order, same wave).
  {
    const int nw = s_nwork;
    const int qh = hl >> 4, ql = hl & 15;
    const int c0 = ql * 8;
    for (int w = hid; w < nw; w += 16) {
      const int a = s_work[w];
      const int d = s_deg[a];
      const float4* wdf4 = reinterpret_cast<const float4*>(W2 + d * (134 * 128));
      float4 acc0 = make_float4(0.f, 0.f, 0.f, 0.f);
      float4 acc1 = make_float4(0.f, 0.f, 0.f, 0.f);
      if (qh == 0) {
        acc0 = *reinterpret_cast<const float4*>(&b2[d * 128 + c0]);
        acc1 = *reinterpret_cast<const float4*>(&b2[d * 128 + c0 + 4]);
      }
      const int kb = qh * 64;
#pragma unroll 4
      for (int j = 0; j < 64; ++j) {
        const float ff = s_x[a * 128 + kb + j];
        const float4 w40 = wdf4[(kb + j) * 32 + 2 * ql];
        const float4 w41 = wdf4[(kb + j) * 32 + 2 * ql + 1];
        acc0.x = fmaf(ff, w40.x, acc0.x); acc0.y = fmaf(ff, w40.y, acc0.y);
        acc0.z = fmaf(ff, w40.z, acc0.z); acc0.w = fmaf(ff, w40.w, acc0.w);
        acc1.x = fmaf(ff, w41.x, acc1.x); acc1.y = fmaf(ff, w41.y, acc1.y);
        acc1.z = fmaf(ff, w41.z, acc1.z); acc1.w = fmaf(ff, w41.w, acc1.w);
      }
#pragma unroll
      for (int t = 0; t < 3; ++t) {
        const int kk = qh * 3 + t;
        const float ff = s_bsum[a * 8 + kk];
        const float4 w40 = wdf4[(128 + kk) * 32 + 2 * ql];
        const float4 w41 = wdf4[(128 + kk) * 32 + 2 * ql + 1];
        acc0.x = fmaf(ff, w40.x, acc0.x); acc0.y = fmaf(ff, w40.y, acc0.y);
        acc0.z = fmaf(ff, w40.z, acc0.z); acc0.w = fmaf(ff, w40.w, acc0.w);
        acc1.x = fmaf(ff, w41.x, acc1.x); acc1.y = fmaf(ff, w41.y, acc1.y);
        acc1.z = fmaf(ff, w41.z, acc1.z); acc1.w = fmaf(ff, w41.w, acc1.w);
      }
      acc0.x += __shfl_xor(acc0.x, 16); acc0.y += __shfl_xor(acc0.y, 16);
      acc0.z += __shfl_xor(acc0.z, 16); acc0.w += __shfl_xor(acc0.w, 16);
      acc1.x += __shfl_xor(acc1.x, 16); acc1.y += __shfl_xor(acc1.y, 16);
      acc1.z += __shfl_xor(acc1.z, 16); acc1.w += __shfl_xor(acc1.w, 16);
      if (qh == 0) {
        *reinterpret_cast<float4*>(&s_x[a * 128 + c0]) =
            make_float4(fmaxf(acc0.x, 0.f), fmaxf(acc0.y, 0.f),
                        fmaxf(acc0.z, 0.f), fmaxf(acc0.w, 0.f));
        *reinterpret_cast<float4*>(&s_x[a * 128 + c0 + 4]) =
            make_float4(fmaxf(acc1.x, 0.f), fmaxf(acc1.y, 0.f),
                        fmaxf(acc1.z, 0.f), fmaxf(acc1.w, 0.f));
      }
    }
  }
  __syncthreads();

  // ---------------- P4: pool2 in place (all rows), work members only, 0-init ----------
  {
    float4 v0 = nbr_wmax(sx4, s_edges, s_deg, (tid + 0 * 512) >> 5, tid & 31);
    float4 v1 = nbr_wmax(sx4, s_edges, s_deg, (tid + 1 * 512) >> 5, tid & 31);
    float4 v2 = nbr_wmax(sx4, s_edges, s_deg, (tid + 2 * 512) >> 5, tid & 31);
    float4 v3 = nbr_wmax(sx4, s_edges, s_deg, (tid + 3 * 512) >> 5, tid & 31);
    __syncthreads();
    sx4[tid + 0 * 512] = v0; sx4[tid + 1 * 512] = v1;
    sx4[tid + 2 * 512] = v2; sx4[tid + 3 * 512] = v3;
  }
  __syncthreads();

  // ---------------- P5: dedup logits GEMM ---------------------------------------------
  // Dense per tile of 8 unique rows: 16 units = 8 row-slots x 2 k-chunks(64); unit
  // (ri,ch) accumulates 4 cols/lane over its chunk and writes D[ch][ri][c] (disjoint ->
  // no atomics; inactive units write zeros). Scatter: logits[a] = D0[ur]+D1[ur]+bo+
  // bsum[a].Wotail for atoms of this tile (ur<0 zero-rows in tile 0).
  // Barriers per tile: dense reads s_x (unique rows) -> bar -> D write -> bar -> scatter
  // writes s_x rows of THIS tile (disjoint from later tiles' unique rows).
  {
    for (int i = tid; i < 768; i += 512) s_wtail[i] = Wo[128 * 128 + i];
    if (tid < 128) s_bo[tid] = bo[tid];
    const int nu = s_nu;
    const int ntile = (nu <= 8) ? 1 : ((nu + 7) >> 3);
    const float4* Wof4 = reinterpret_cast<const float4*>(Wo);
    const int ri = hid & 7, ch = hid >> 3;
    const int c0 = hl * 4;
    for (int t = 0; t < ntile; ++t) {
      const int u = t * 8 + ri;
      float4 acc = make_float4(0.f, 0.f, 0.f, 0.f);
      if (u < nu) {
        const int arow = s_uniq[u] * 128;
        const int kb = ch * 64;
#pragma unroll 4
        for (int j = 0; j < 64; ++j) {
          const float ff = s_x[arow + kb + j];
          const float4 w4 = Wof4[(kb + j) * 32 + hl];
          acc.x = fmaf(ff, w4.x, acc.x); acc.y = fmaf(ff, w4.y, acc.y);
          acc.z = fmaf(ff, w4.z, acc.z); acc.w = fmaf(ff, w4.w, acc.w);
        }
      }
      __syncthreads();   // dense reads done (also: wtail/bo staged; prev scatter drained)
      *reinterpret_cast<float4*>(&s_D[ch * 1024 + ri * 128 + c0]) = acc;
      __syncthreads();   // D ready
      for (int e = tid; e < 64 * 128; e += 512) {
        const int a = e >> 7, c = e & 127;
        const int ur = s_urow[a];
        const int ta = (ur < 0) ? 0 : (ur >> 3);
        if (ta == t) {
          float acc2 = s_bo[c];
#pragma unroll
          for (int kk = 0; kk < 6; ++kk)
            acc2 = fmaf(s_bsum[a * 8 + kk], s_wtail[kk * 128 + c], acc2);
          if (ur >= 0) {
            const int lr = (ur - t * 8) * 128 + c;
            acc2 += s_D[lr] + s_D[1024 + lr];
          }
          s_x[a * 128 + c] = acc2;
        }
      }
      // no barrier needed here for s_x (next tile's dense reads disjoint rows);
      // the next iteration's first barrier orders this scatter's D reads vs D rewrite.
    }
  }
  __syncthreads();

  // ---------------- P6: per-atom softmax over 128, 8 lanes/atom, in registers ---------
  {
    const int a = tid >> 3, q = tid & 7;     // 64 atoms x 8 lanes
    float* base = &s_x[a * 128 + q * 16];
    const float4 v0 = *reinterpret_cast<const float4*>(base + ((0 + tid) & 3) * 4);
    const float4 v1 = *reinterpret_cast<const float4*>(base + ((1 + tid) & 3) * 4);
    const float4 v2 = *reinterpret_cast<const float4*>(base + ((2 + tid) & 3) * 4);
    const float4 v3 = *reinterpret_cast<const float4*>(base + ((3 + tid) & 3) * 4);
    float mx = fmaxf(fmaxf(fmaxf(v0.x, v0.y), fmaxf(v0.z, v0.w)),
                     fmaxf(fmaxf(v1.x, v1.y), fmaxf(v1.z, v1.w)));
    mx = fmaxf(mx, fmaxf(fmaxf(fmaxf(v2.x, v2.y), fmaxf(v2.z, v2.w)),
                         fmaxf(fmaxf(v3.x, v3.y), fmaxf(v3.z, v3.w))));
    mx = fmaxf(mx, __shfl_xor(mx, 1));
    mx = fmaxf(mx, __shfl_xor(mx, 2));
    mx = fmaxf(mx, __shfl_xor(mx, 4));
    float4 e0, e1, e2, e3;
    e0.x = __expf(v0.x - mx); e0.y = __expf(v0.y - mx); e0.z = __expf(v0.z - mx); e0.w = __expf(v0.w - mx);
    e1.x = __expf(v1.x - mx); e1.y = __expf(v1.y - mx); e1.z = __expf(v1.z - mx); e1.w = __expf(v1.w - mx);
    e2.x = __expf(v2.x - mx); e2.y = __expf(v2.y - mx); e2.z = __expf(v2.z - mx); e2.w = __expf(v2.w - mx);
    e3.x = __expf(v3.x - mx); e3.y = __expf(v3.y - mx); e3.z = __expf(v3.z - mx); e3.w = __expf(v3.w - mx);
    float sm = e0.x + e0.y + e0.z + e0.w;
    sm += e1.x + e1.y + e1.z + e1.w;
    sm += e2.x + e2.y + e2.z + e2.w;
    sm += e3.x + e3.y + e3.z + e3.w;
    *reinterpret_cast<float4*>(base + ((0 + tid) & 3) * 4) = e0;
    *reinterpret_cast<float4*>(base + ((1 + tid) & 3) * 4) = e1;
    *reinterpret_cast<float4*>(base + ((2 + tid) & 3) * 4) = e2;
    *reinterpret_cast<float4*>(base + ((3 + tid) & 3) * 4) = e3;
    sm += __shfl_xor(sm, 1);
    sm += __shfl_xor(sm, 2);
    sm += __shfl_xor(sm, 4);
    if (q == 0) s_rsum[a] = (s_deg[a] != 0) ? (1.f / sm) : 0.f;
  }
  __syncthreads();

  // ---------------- P7: fingerprint (4 partials x 128, aliases dead s_D) --------------
  {
    const int c = tid & 127, quarter = tid >> 7;   // 0..3
    float s = 0.f;
    for (int a2 = quarter * 16; a2 < quarter * 16 + 16; ++a2)
      s = fmaf(s_x[a2 * 128 + c], s_rsum[a2], s);
    s_fp[quarter * 128 + c] = s;
  }
  __syncthreads();
  if (tid < 128) s_fp[tid] += s_fp[128 + tid] + s_fp[256 + tid] + s_fp[384 + tid];
  __syncthreads();

  // ---------------- P8: MLP head ------------------------------------------------------
  if (tid < 64) {
    float acc = bm1[tid];
    for (int k = 0; k < 128; ++k) acc = fmaf(s_fp[k], Wm1[k * 64 + tid], acc);
    s_h1[tid] = fmaxf(acc, 0.f);
  }
  __syncthreads();
  if (tid < 32) {
    float acc = bm2[tid];
    for (int k = 0; k < 64; ++k) acc = fmaf(s_h1[k], Wm2[k * 32 + tid], acc);
    s_h2[tid] = fmaxf(acc, 0.f);
  }
  __syncthreads();
  if (tid < 64) {
    float p = (tid < 32) ? s_h2[tid] * Wm3[tid] : 0.f;
#pragma unroll
    for (int off = 32; off > 0; off >>= 1) p += __shfl_xor(p, off);
    if (tid == 0) out[b] = p + bm3[0];
  }
}

extern "C" void kernel_launch(void* const* d_in, const int* in_sizes, int n_in,
                              void* d_out, int out_size, void* d_ws, size_t ws_size,
                              hipStream_t stream) {
  const float* atoms = (const float*)d_in[0];
  const float* bonds = (const float*)d_in[1];
  const int*   edges = (const int*)d_in[2];
  const float* W1  = (const float*)d_in[3];
  const float* b1  = (const float*)d_in[4];
  const float* W2  = (const float*)d_in[5];
  const float* b2  = (const float*)d_in[6];
  const float* Wo  = (const float*)d_in[7];
  const float* bo  = (const float*)d_in[8];
  const float* Wm1 = (const float*)d_in[9];
  const float* bm1 = (const float*)d_in[10];
  const float* Wm2 = (const float*)d_in[11];
  const float* bm2 = (const float*)d_in[12];
  const float* Wm3 = (const float*)d_in[13];
  const float* bm3 = (const float*)d_in[14];
  float* out = (float*)d_out;

  const int B = out_size;  // 4096 molecules
  qsar_fused<<<dim3(B), dim3(512), 0, stream>>>(
      atoms, bonds, edges, W1, b1, W2, b2, Wo, bo,
      Wm1, bm1, Wm2, bm2, Wm3, bm3, out);
}

// Round 13
// 266.332 us; speedup vs baseline: 1.8757x; 1.3986x over previous
//
#include <hip/hip_runtime.h>
#include <math.h>

// QSAR fused pipeline, ONE BLOCK OF 512 THREADS PER MOLECULE (R7 base = 239us proven).
// B=4096, A=64, D=6, AF=37, BF=6, H=128.
// R13 = R7 + P5 dedup, zero-occupancy-cost edition:
//  - x2p[a] depends only on a's work-member set; equal masks -> identical rows (~7 unique).
//  - dedup scan in wave-0 REGISTERS via __shfl (no LDS masks); +516B LDS only.
//  - P4: pool2 for unique rows only (register-stage+barrier, R7 shape).
//  - P5a: own-row dense GEMV per unique row (R7 conv2's proven shape), in place.
//  - P5b: scatter logits[a] = dense[rep(a)] + bo + bsum.Wotail, 16 staged regs + barrier.
// Envelope: (512,8); LDS 40464B -> still 4 blocks/CU. Spill tripwire: WRITE_SIZE ~128KB.

__device__ __forceinline__ float4 max4(float4 a, float4 b) {
  return make_float4(fmaxf(a.x, b.x), fmaxf(a.y, b.y), fmaxf(a.z, b.z), fmaxf(a.w, b.w));
}

__device__ __forceinline__ float4 nbr_max(const float4* sx4, const int* se, int a, int c4) {
  float4 m = sx4[a * 32 + c4];
#pragma unroll
  for (int d = 0; d < 6; ++d) {
    int e = se[a * 6 + d];
    if (e >= 0) m = max4(m, sx4[e * 32 + c4]);
  }
  return m;
}

__device__ __forceinline__ float4 nbr_sum(const float4* sx4, const int* se, int a, int c4) {
  float4 s = sx4[a * 32 + c4];
#pragma unroll
  for (int d = 0; d < 6; ++d) {
    int e = se[a * 6 + d];
    if (e >= 0) {
      float4 v = sx4[e * 32 + c4];
      s.x += v.x; s.y += v.y; s.z += v.z; s.w += v.w;
    }
  }
  return s;
}

// pool2: max over WORK members only; non-work x2 rows implicitly 0, relu>=0 -> 0-init exact.
__device__ __forceinline__ float4 nbr_wmax(const float4* sx4, const int* se, const int* sdeg,
                                           int a, int c4) {
  float4 m = make_float4(0.f, 0.f, 0.f, 0.f);
  if (sdeg[a] < 6) m = max4(m, sx4[a * 32 + c4]);
#pragma unroll
  for (int d = 0; d < 6; ++d) {
    int e = se[a * 6 + d];
    if (e >= 0 && sdeg[e] < 6) m = max4(m, sx4[e * 32 + c4]);
  }
  return m;
}

__global__ __launch_bounds__(512, 8) void qsar_fused(
    const float* __restrict__ atoms, const float* __restrict__ bonds,
    const int* __restrict__ edges,
    const float* __restrict__ W1, const float* __restrict__ b1,
    const float* __restrict__ W2, const float* __restrict__ b2,
    const float* __restrict__ Wo, const float* __restrict__ bo,
    const float* __restrict__ Wm1, const float* __restrict__ bm1,
    const float* __restrict__ Wm2, const float* __restrict__ bm2,
    const float* __restrict__ Wm3, const float* __restrict__ bm3,
    float* __restrict__ out)
{
  const int b    = blockIdx.x;
  const int tid  = threadIdx.x;        // 0..511
  const int hid  = tid >> 5;           // half-wave unit id 0..15
  const int hl   = tid & 31;           // lane in half-wave

  __shared__ float s_x[64 * 128];      // 32768 B
  __shared__ float s_sa[608];          // conv1 gather 16x38; later fp(512)+h1(64)+h2(32)
  __shared__ float s_bsum[64 * 8];     // 2048 B
  __shared__ int   s_edges[64 * 6];    // 1536 B
  __shared__ int   s_deg[64];
  __shared__ int   s_work[64];         // deg<6 atoms
  __shared__ int   s_urow[64];         // unique-row id per atom, -1 if zero x2p row
  __shared__ int   s_uniq[64];         // atom id of each unique row
  __shared__ float s_rsum[64];
  __shared__ int   s_nwork, s_nu;

  float4* sx4  = reinterpret_cast<float4*>(s_x);
  float*  s_fp = s_sa;                 // 512 floats (4 partials x 128)
  float*  s_h1 = s_sa + 512;           // 64
  float*  s_h2 = s_sa + 576;           // 32

  // ---------------- P0: stage edges, bsum; zero s_x; reset counters -------------------
  {
    const int* ge = edges + (size_t)b * (64 * 6);
    for (int i = tid; i < 64 * 6; i += 512) s_edges[i] = ge[i];
    const float* gb = bonds + (size_t)b * (64 * 36);
    for (int i = tid; i < 64 * 6; i += 512) {
      int a = i / 6, f = i - a * 6;
      float s = 0.f;
#pragma unroll
      for (int d = 0; d < 6; ++d) s += gb[a * 36 + d * 6 + f];
      s_bsum[a * 8 + f] = s;
    }
#pragma unroll
    for (int j = 0; j < 4; ++j) sx4[tid + j * 512] = make_float4(0.f, 0.f, 0.f, 0.f);
    if (tid == 0) { s_nwork = 0; s_nu = 0; }
  }
  __syncthreads();

  // ---------------- P0b: degree + worklist --------------------------------------------
  if (tid < 64) {
    int dcnt = 0;
#pragma unroll
    for (int d = 0; d < 6; ++d) dcnt += (s_edges[tid * 6 + d] >= 0) ? 1 : 0;
    s_deg[tid] = dcnt;
    if (dcnt < 6) { int p = atomicAdd(&s_nwork, 1); s_work[p] = tid; }
  }
  __syncthreads();

  // ---------------- P0c: x2p dedup in wave-0 registers (shfl scan) --------------------
  // mask[a] = set of work atoms in a's closed neighborhood; equal masks -> equal x2p.
  if (tid < 64) {
    unsigned int mlo = 0u, mhi = 0u;
    if (s_deg[tid] < 6) { if (tid < 32) mlo |= 1u << tid; else mhi |= 1u << (tid - 32); }
#pragma unroll
    for (int d = 0; d < 6; ++d) {
      int e = s_edges[tid * 6 + d];
      if (e >= 0 && s_deg[e] < 6) { if (e < 32) mlo |= 1u << e; else mhi |= 1u << (e - 32); }
    }
    const bool nz = (mlo | mhi) != 0u;
    int rep = tid;
    for (int bb = 0; bb < 64; ++bb) {
      const unsigned int blo = (unsigned int)__shfl((int)mlo, bb);
      const unsigned int bhi = (unsigned int)__shfl((int)mhi, bb);
      if (bb < tid && blo == mlo && bhi == mhi && rep == tid) rep = bb;
    }
    int u = -1;
    if (nz && rep == tid) u = atomicAdd(&s_nu, 1);
    const int urep = __shfl(u, rep);
    s_urow[tid] = nz ? urep : -1;
    if (u >= 0) s_uniq[u] = tid;
  }
  // (visible after the next barrier inside P1)

  // ---------------- P1: conv1, 16 half-wave GEMV units, chunks of <=16 work atoms -----
  {
    const int nw = s_nwork;
    const float* ga = atoms + (size_t)b * (64 * 37);
    const int c0 = hl * 4;
    for (int cb = 0; cb < nw; cb += 16) {
      const int cnt = (nw - cb < 16) ? (nw - cb) : 16;
      for (int i = tid; i < cnt * 37; i += 512) {
        int wi = i / 37, k = i - wi * 37;
        int a = s_work[cb + wi];
        float f = ga[a * 37 + k];
#pragma unroll
        for (int d = 0; d < 6; ++d) {
          int e = s_edges[a * 6 + d];
          if (e >= 0) f += ga[e * 37 + k];
        }
        s_sa[wi * 38 + k] = f;
      }
      __syncthreads();
      for (int w = hid; w < cnt; w += 16) {
        const int a = s_work[cb + w];
        const int d = s_deg[a];
        const float4* wdf4 = reinterpret_cast<const float4*>(W1 + d * (43 * 128));
        float4 acc = *reinterpret_cast<const float4*>(&b1[d * 128 + c0]);
#pragma unroll 4
        for (int k = 0; k < 37; ++k) {
          const float ff = s_sa[w * 38 + k];
          const float4 w4 = wdf4[k * 32 + hl];
          acc.x = fmaf(ff, w4.x, acc.x); acc.y = fmaf(ff, w4.y, acc.y);
          acc.z = fmaf(ff, w4.z, acc.z); acc.w = fmaf(ff, w4.w, acc.w);
        }
#pragma unroll
        for (int kk = 0; kk < 6; ++kk) {
          const float ff = s_bsum[a * 8 + kk];
          const float4 w4 = wdf4[(37 + kk) * 32 + hl];
          acc.x = fmaf(ff, w4.x, acc.x); acc.y = fmaf(ff, w4.y, acc.y);
          acc.z = fmaf(ff, w4.z, acc.z); acc.w = fmaf(ff, w4.w, acc.w);
        }
        *reinterpret_cast<float4*>(&s_x[a * 128 + c0]) =
            make_float4(fmaxf(acc.x, 0.f), fmaxf(acc.y, 0.f),
                        fmaxf(acc.z, 0.f), fmaxf(acc.w, 0.f));
      }
      __syncthreads();
    }
  }
  __syncthreads();

  // ---------------- P2: pool1 in place (all rows), float4, 4 elems/thread -------------
  {
    float4 v0 = nbr_max(sx4, s_edges, (tid + 0 * 512) >> 5, tid & 31);
    float4 v1 = nbr_max(sx4, s_edges, (tid + 1 * 512) >> 5, tid & 31);
    float4 v2 = nbr_max(sx4, s_edges, (tid + 2 * 512) >> 5, tid & 31);
    float4 v3 = nbr_max(sx4, s_edges, (tid + 3 * 512) >> 5, tid & 31);
    __syncthreads();
    sx4[tid + 0 * 512] = v0; sx4[tid + 1 * 512] = v1;
    sx4[tid + 2 * 512] = v2; sx4[tid + 3 * 512] = v3;
  }
  __syncthreads();

  // ---------------- P2b: ysum for work rows in place ----------------------------------
  {
    const float4 z = make_float4(0.f, 0.f, 0.f, 0.f);
    float4 v0 = z, v1 = z, v2 = z, v3 = z;
    if (s_deg[(tid + 0 * 512) >> 5] < 6) v0 = nbr_sum(sx4, s_edges, (tid + 0 * 512) >> 5, tid & 31);
    if (s_deg[(tid + 1 * 512) >> 5] < 6) v1 = nbr_sum(sx4, s_edges, (tid + 1 * 512) >> 5, tid & 31);
    if (s_deg[(tid + 2 * 512) >> 5] < 6) v2 = nbr_sum(sx4, s_edges, (tid + 2 * 512) >> 5, tid & 31);
    if (s_deg[(tid + 3 * 512) >> 5] < 6) v3 = nbr_sum(sx4, s_edges, (tid + 3 * 512) >> 5, tid & 31);
    __syncthreads();
    if (s_deg[(tid + 0 * 512) >> 5] < 6) sx4[tid + 0 * 512] = v0;
    if (s_deg[(tid + 1 * 512) >> 5] < 6) sx4[tid + 1 * 512] = v1;
    if (s_deg[(tid + 2 * 512) >> 5] < 6) sx4[tid + 2 * 512] = v2;
    if (s_deg[(tid + 3 * 512) >> 5] < 6) sx4[tid + 3 * 512] = v3;
  }
  __syncthreads();

  // ---------------- P3: conv2, 16 half-wave units, own-row read / own-row write -------
  {
    const int nw = s_nwork;
    const int c0 = hl * 4;
    for (int w = hid; w < nw; w += 16) {
      const int a = s_work[w];
      const int d = s_deg[a];
      const float4* wdf4 = reinterpret_cast<const float4*>(W2 + d * (134 * 128));
      float4 acc = *reinterpret_cast<const float4*>(&b2[d * 128 + c0]);
#pragma unroll 4
      for (int k = 0; k < 128; ++k) {
        const float ff = s_x[a * 128 + k];
        const float4 w4 = wdf4[k * 32 + hl];
        acc.x = fmaf(ff, w4.x, acc.x); acc.y = fmaf(ff, w4.y, acc.y);
        acc.z = fmaf(ff, w4.z, acc.z); acc.w = fmaf(ff, w4.w, acc.w);
      }
#pragma unroll
      for (int kk = 0; kk < 6; ++kk) {
        const float ff = s_bsum[a * 8 + kk];
        const float4 w4 = wdf4[(128 + kk) * 32 + hl];
        acc.x = fmaf(ff, w4.x, acc.x); acc.y = fmaf(ff, w4.y, acc.y);
        acc.z = fmaf(ff, w4.z, acc.z); acc.w = fmaf(ff, w4.w, acc.w);
      }
      *reinterpret_cast<float4*>(&s_x[a * 128 + c0]) =
          make_float4(fmaxf(acc.x, 0.f), fmaxf(acc.y, 0.f),
                      fmaxf(acc.z, 0.f), fmaxf(acc.w, 0.f));
    }
  }
  __syncthreads();

  // ---------------- P4: pool2 for UNIQUE rows only (register-stage + scatter) ---------
  // Reads x2 (work rows); writes x2p ONLY at unique-rep rows after the barrier.
  {
    const int lim = s_nu * 32;          // float4 slots (nu<=64 -> lim<=2048 = 4*512)
    const float4 z = make_float4(0.f, 0.f, 0.f, 0.f);
    float4 v0 = z, v1 = z, v2 = z, v3 = z;
    const int i0 = tid, i1 = tid + 512, i2 = tid + 1024, i3 = tid + 1536;
    if (i0 < lim) v0 = nbr_wmax(sx4, s_edges, s_deg, s_uniq[i0 >> 5], i0 & 31);
    if (i1 < lim) v1 = nbr_wmax(sx4, s_edges, s_deg, s_uniq[i1 >> 5], i1 & 31);
    if (i2 < lim) v2 = nbr_wmax(sx4, s_edges, s_deg, s_uniq[i2 >> 5], i2 & 31);
    if (i3 < lim) v3 = nbr_wmax(sx4, s_edges, s_deg, s_uniq[i3 >> 5], i3 & 31);
    __syncthreads();
    if (i0 < lim) sx4[s_uniq[i0 >> 5] * 32 + (i0 & 31)] = v0;
    if (i1 < lim) sx4[s_uniq[i1 >> 5] * 32 + (i1 & 31)] = v1;
    if (i2 < lim) sx4[s_uniq[i2 >> 5] * 32 + (i2 & 31)] = v2;
    if (i3 < lim) sx4[s_uniq[i3 >> 5] * 32 + (i3 & 31)] = v3;
  }
  __syncthreads();

  // ---------------- P5a: dense GEMV per unique row, in place (conv2's proven shape) ---
  // Unit reads ONLY its own row's x2p (all k), writes its 4 cols after all reads.
  {
    const int nu = s_nu;
    const int c0 = hl * 4;
    const float4* Wof4 = reinterpret_cast<const float4*>(Wo);
    for (int w = hid; w < nu; w += 16) {
      const int arow = s_uniq[w] * 128;
      float4 acc = make_float4(0.f, 0.f, 0.f, 0.f);
#pragma unroll 4
      for (int k = 0; k < 128; ++k) {
        const float ff = s_x[arow + k];
        const float4 w4 = Wof4[k * 32 + hl];
        acc.x = fmaf(ff, w4.x, acc.x); acc.y = fmaf(ff, w4.y, acc.y);
        acc.z = fmaf(ff, w4.z, acc.z); acc.w = fmaf(ff, w4.w, acc.w);
      }
      *reinterpret_cast<float4*>(&s_x[arow + c0]) = acc;   // dense only (no bias/tail)
    }
  }
  __syncthreads();

  // ---------------- P5b: scatter logits[a] = dense[rep(a)] + bo + bsum.Wotail ---------
  // Stage all 16 values (reads of dense rows) before the barrier, then write.
  {
    float st[16];
#pragma unroll
    for (int j = 0; j < 16; ++j) {
      const int e = tid + j * 512;
      const int a = e >> 7, c = e & 127;
      const int ur = s_urow[a];
      float acc = bo[c];
#pragma unroll
      for (int kk = 0; kk < 6; ++kk)
        acc = fmaf(s_bsum[a * 8 + kk], Wo[(128 + kk) * 128 + c], acc);
      if (ur >= 0) acc += s_x[s_uniq[ur] * 128 + c];
      st[j] = acc;
    }
    __syncthreads();
#pragma unroll
    for (int j = 0; j < 16; ++j) s_x[tid + j * 512] = st[j];
  }
  __syncthreads();

  // ---------------- P6: per-atom softmax over 128, 8 lanes/atom, in registers ---------
  {
    const int a = tid >> 3, q = tid & 7;     // 64 atoms x 8 lanes
    float* base = &s_x[a * 128 + q * 16];
    const float4 v0 = *reinterpret_cast<const float4*>(base + ((0 + tid) & 3) * 4);
    const float4 v1 = *reinterpret_cast<const float4*>(base + ((1 + tid) & 3) * 4);
    const float4 v2 = *reinterpret_cast<const float4*>(base + ((2 + tid) & 3) * 4);
    const float4 v3 = *reinterpret_cast<const float4*>(base + ((3 + tid) & 3) * 4);
    float mx = fmaxf(fmaxf(fmaxf(v0.x, v0.y), fmaxf(v0.z, v0.w)),
                     fmaxf(fmaxf(v1.x, v1.y), fmaxf(v1.z, v1.w)));
    mx = fmaxf(mx, fmaxf(fmaxf(fmaxf(v2.x, v2.y), fmaxf(v2.z, v2.w)),
                         fmaxf(fmaxf(v3.x, v3.y), fmaxf(v3.z, v3.w))));
    mx = fmaxf(mx, __shfl_xor(mx, 1));
    mx = fmaxf(mx, __shfl_xor(mx, 2));
    mx = fmaxf(mx, __shfl_xor(mx, 4));
    float4 e0, e1, e2, e3;
    e0.x = __expf(v0.x - mx); e0.y = __expf(v0.y - mx); e0.z = __expf(v0.z - mx); e0.w = __expf(v0.w - mx);
    e1.x = __expf(v1.x - mx); e1.y = __expf(v1.y - mx); e1.z = __expf(v1.z - mx); e1.w = __expf(v1.w - mx);
    e2.x = __expf(v2.x - mx); e2.y = __expf(v2.y - mx); e2.z = __expf(v2.z - mx); e2.w = __expf(v2.w - mx);
    e3.x = __expf(v3.x - mx); e3.y = __expf(v3.y - mx); e3.z = __expf(v3.z - mx); e3.w = __expf(v3.w - mx);
    float sm = e0.x + e0.y + e0.z + e0.w;
    sm += e1.x + e1.y + e1.z + e1.w;
    sm += e2.x + e2.y + e2.z + e2.w;
    sm += e3.x + e3.y + e3.z + e3.w;
    *reinterpret_cast<float4*>(base + ((0 + tid) & 3) * 4) = e0;
    *reinterpret_cast<float4*>(base + ((1 + tid) & 3) * 4) = e1;
    *reinterpret_cast<float4*>(base + ((2 + tid) & 3) * 4) = e2;
    *reinterpret_cast<float4*>(base + ((3 + tid) & 3) * 4) = e3;
    sm += __shfl_xor(sm, 1);
    sm += __shfl_xor(sm, 2);
    sm += __shfl_xor(sm, 4);
    if (q == 0) s_rsum[a] = (s_deg[a] != 0) ? (1.f / sm) : 0.f;
  }
  __syncthreads();

  // ---------------- P7: fingerprint (4 partials x 128, aliases dead s_sa) -------------
  {
    const int c = tid & 127, quarter = tid >> 7;   // 0..3
    float s = 0.f;
    for (int a2 = quarter * 16; a2 < quarter * 16 + 16; ++a2)
      s = fmaf(s_x[a2 * 128 + c], s_rsum[a2], s);
    s_fp[quarter * 128 + c] = s;
  }
  __syncthreads();
  if (tid < 128) s_fp[tid] += s_fp[128 + tid] + s_fp[256 + tid] + s_fp[384 + tid];
  __syncthreads();

  // ---------------- P8: MLP head ------------------------------------------------------
  if (tid < 64) {
    float acc = bm1[tid];
    for (int k = 0; k < 128; ++k) acc = fmaf(s_fp[k], Wm1[k * 64 + tid], acc);
    s_h1[tid] = fmaxf(acc, 0.f);
  }
  __syncthreads();
  if (tid < 32) {
    float acc = bm2[tid];
    for (int k = 0; k < 64; ++k) acc = fmaf(s_h1[k], Wm2[k * 32 + tid], acc);
    s_h2[tid] = fmaxf(acc, 0.f);
  }
  __syncthreads();
  if (tid < 64) {
    float p = (tid < 32) ? s_h2[tid] * Wm3[tid] : 0.f;
#pragma unroll
    for (int off = 32; off > 0; off >>= 1) p += __shfl_xor(p, off);
    if (tid == 0) out[b] = p + bm3[0];
  }
}

extern "C" void kernel_launch(void* const* d_in, const int* in_sizes, int n_in,
                              void* d_out, int out_size, void* d_ws, size_t ws_size,
                              hipStream_t stream) {
  const float* atoms = (const float*)d_in[0];
  const float* bonds = (const float*)d_in[1];
  const int*   edges = (const int*)d_in[2];
  const float* W1  = (const float*)d_in[3];
  const float* b1  = (const float*)d_in[4];
  const float* W2  = (const float*)d_in[5];
  const float* b2  = (const float*)d_in[6];
  const float* Wo  = (const float*)d_in[7];
  const float* bo  = (const float*)d_in[8];
  const float* Wm1 = (const float*)d_in[9];
  const float* bm1 = (const float*)d_in[10];
  const float* Wm2 = (const float*)d_in[11];
  const float* bm2 = (const float*)d_in[12];
  const float* Wm3 = (const float*)d_in[13];
  const float* bm3 = (const float*)d_in[14];
  float* out = (float*)d_out;

  const int B = out_size;  // 4096 molecules
  qsar_fused<<<dim3(B), dim3(512), 0, stream>>>(
      atoms, bonds, edges, W1, b1, W2, b2, Wo, bo,
      Wm1, bm1, Wm2, bm2, Wm3, bm3, out);
}